// Round 6
// baseline (1196.409 us; speedup 1.0000x reference)
//
#include <hip/hip_runtime.h>
#include <math.h>

// MetaNETS Langevin sampler, MI355X — round 6: alias tau buffer onto h1 buffer.
// R5 analysis: VALU-issue+occupancy bound (VALUBusy 49.5%, Occ 31.6%), LDS
// 40.4KB/block capped residency at 4 blocks/CU. Wave w's A-frag loads consume
// h1f units {kc*4+w} and its tau scatter writes the SAME unit set strictly
// after the af registers are loaded -> tau can alias h1f with NO extra
// barrier. LDS -> ~23.9KB -> 6 blocks/CU (24 waves, VGPR 80 allows 6/SIMD).

#define B_TOT 2048
#define NPT   64
#define ZD    64
#define HD    128

typedef short bh8 __attribute__((ext_vector_type(8)));   // 8 x bf16 (4 VGPR)
typedef float fx4 __attribute__((ext_vector_type(4)));   // MFMA C/D

__device__ __forceinline__ float sigf(float x) {
  return __builtin_amdgcn_rcpf(1.0f + __expf(-x));
}
__device__ __forceinline__ unsigned int bfb(float x) {   // fp32 -> bf16 bits (RNE)
  unsigned int u = __float_as_uint(x);
  u += 0x7FFFu + ((u >> 16) & 1u);
  return u >> 16;
}
__device__ __forceinline__ unsigned int packbf(float a, float b) {
  unsigned int ua = __float_as_uint(a), ub = __float_as_uint(b);
  ua += 0x7FFFu + ((ua >> 16) & 1u);
  ub += 0x7FFFu + ((ub >> 16) & 1u);
  return (ua >> 16) | (ub & 0xFFFF0000u);
}
__device__ __forceinline__ float wsum64(float v) {
  #pragma unroll
  for (int d = 1; d < 64; d <<= 1) v += __shfl_xor(v, d, 64);
  return v;
}
__device__ __forceinline__ void wave_sync() {   // intra-wave LDS order + drain
  __builtin_amdgcn_wave_barrier();
  __builtin_amdgcn_s_waitcnt(0xC07F);           // lgkmcnt(0)
  __builtin_amdgcn_wave_barrier();
}

// B-frag arrays (bf16): for W[K=128][N=128] with K = contraction:
//   frag[((kc*8+nt)*64 + L)*8 + j] = W[kc*32 + (L>>4)*8 + j][nt*16 + (L&15)]
// arr0: Wd2 (fwd)   arr1: Wd2^T (bwd)   arr2: We2   arr3: We3
__global__ __launch_bounds__(256)
void prep_kernel(const float* __restrict__ Wd2, const float* __restrict__ We2,
                 const float* __restrict__ We3, ushort* __restrict__ ws) {
  const int id = blockIdx.x * 256 + threadIdx.x;   // 65536 total
  const int arr = id >> 14;
  const int e = id & 16383;
  const int j = e & 7, L = (e >> 3) & 63, nt = (e >> 9) & 7, kc = e >> 12;
  const int kk = kc * 32 + (L >> 4) * 8 + j, nn = nt * 16 + (L & 15);
  float v;
  if      (arr == 0) v = Wd2[kk * HD + nn];
  else if (arr == 1) v = Wd2[nn * HD + kk];    // Wd2^T
  else if (arr == 2) v = We2[kk * HD + nn];
  else               v = We3[kk * HD + nn];
  ws[id] = (ushort)bfb(v);
}

__global__ __launch_bounds__(256, 1)
void metanets_kernel(
    const float* __restrict__ x_ctx, const float* __restrict__ y_ctx,
    const float* __restrict__ mask,  const float* __restrict__ z0,
    const float* __restrict__ noises,
    const float* __restrict__ We1, const float* __restrict__ be1,
    const float* __restrict__ be2, const float* __restrict__ be3,
    const float* __restrict__ Wd1, const float* __restrict__ bd1,
    const float* __restrict__ bd2, const float* __restrict__ Wd3,
    const float* __restrict__ bd3,
    const float* __restrict__ Wf1, const float* __restrict__ bf1,
    const float* __restrict__ Wf2, const float* __restrict__ bf2,
    const float* __restrict__ Wf3, const float* __restrict__ bf3,
    const ushort* __restrict__ wsfrag,
    float* __restrict__ out, int steps, float dt, float dco)
{
  // h1f doubles as the tau buffer: wave w's tau scatter targets exactly the
  // units {x*4+w} it already consumed via its af loads (wave-local overwrite).
  __shared__ unsigned int h1f[4096];
  __shared__ float zsh[64];
  __shared__ float zw1[128];
  __shared__ float rsh[128];
  __shared__ float dsumP[512];
  __shared__ float dsumC[128];
  __shared__ float f1sh[128];           // be2 staging, then drift hidden1
  __shared__ float f2sh[128];           // be3 staging, then drift hidden2
  __shared__ float bgz[128];
  __shared__ float bd2sh[128], wd3sh[128], wx0sh[128], wx1sh[128];

  unsigned int* const tauf = h1f;

  const int tid = threadIdx.x;
  const int lane = tid & 63;                                  // context point
  const int w = __builtin_amdgcn_readfirstlane(tid >> 6);     // wave = m-tile
  const int b = blockIdx.x;
  const int rr = lane & 15, qq = lane >> 4;

  const bh8* Wd2f  = (const bh8*)(wsfrag);
  const bh8* Wd2Tf = (const bh8*)(wsfrag + 16384);
  const bh8* We2f  = (const bh8*)(wsfrag + 32768);
  const bh8* We3f  = (const bh8*)(wsfrag + 49152);

  const float x0v = x_ctx[(b*NPT + lane)*2 + 0];
  const float x1v = x_ctx[(b*NPT + lane)*2 + 1];
  const float yv  = y_ctx[b*NPT + lane];
  const float mkv = mask[b*NPT + lane];
  const float inv_msum = 1.0f / fmaxf(wsum64(mkv), 1e-6f);
  const float bd3v = bd3[0];

  // per-lane data for the 4 C-rows this lane holds (points 16w+4*qq+g)
  float x0q[4], x1q[4], yq[4], mkq[4];
  #pragma unroll
  for (int g = 0; g < 4; ++g) {
    const int src = (w << 4) | (qq << 2) | g;
    x0q[g] = __shfl(x0v, src, 64);
    x1q[g] = __shfl(x1v, src, 64);
    yq[g]  = __shfl(yv,  src, 64);
    mkq[g] = __shfl(mkv, src, 64);
  }

  if (tid < 64) zsh[tid] = z0[b*ZD + tid];
  if (tid < 128) {
    bd2sh[tid] = bd2[tid];
    wd3sh[tid] = Wd3[tid];
    wx0sh[tid] = Wd1[64*HD + tid];
    wx1sh[tid] = Wd1[65*HD + tid];
    f1sh[tid]  = be2[tid];
    f2sh[tid]  = be3[tid];
  }
  __syncthreads();

  // ================= encoder =================
  // enc L1: lane=point, wave w computes k-slice kc=w, writes A-frag layout
  #pragma unroll
  for (int quad = 0; quad < 4; ++quad) {
    unsigned int pw[4];
    #pragma unroll
    for (int jj = 0; jj < 8; jj += 2) {
      const int k = 32*w + 8*quad + jj;
      const float sA = be1[k]   + x0v*We1[k]   + x1v*We1[HD+k]   + yv*We1[2*HD+k];
      const float sB = be1[k+1] + x0v*We1[k+1] + x1v*We1[HD+k+1] + yv*We1[2*HD+k+1];
      pw[jj>>1] = packbf(sA*sigf(sA), sB*sigf(sB));
    }
    uint4 v4; v4.x = pw[0]; v4.y = pw[1]; v4.z = pw[2]; v4.w = pw[3];
    ((uint4*)h1f)[(w*4 + (lane>>4))*64 + quad*16 + (lane&15)] = v4;
  }
  __syncthreads();

  // enc L2 (MFMA): H2 = silu(H1 @ We2 + be2) -> tauf (A-frag layout, aliased)
  {
    bh8 af[4];
    #pragma unroll
    for (int kc = 0; kc < 4; ++kc)
      af[kc] = ((const bh8*)h1f)[(kc*4 + w)*64 + lane];
    wave_sync();   // af in regs before the aliased scatter below
    #pragma unroll 1
    for (int half = 0; half < 2; ++half) {
      const int h4 = half*4;
      fx4 acc[4];
      #pragma unroll
      for (int i = 0; i < 4; ++i) {
        const float bv = f1sh[(h4+i)*16 + rr];
        acc[i] = (fx4){bv, bv, bv, bv};
      }
      #pragma unroll
      for (int i = 0; i < 4; ++i) {
        const int nt = h4 + i;
        const bh8 b0 = We2f[(0*8+nt)*64 + lane];
        const bh8 b1 = We2f[(1*8+nt)*64 + lane];
        const bh8 b2 = We2f[(2*8+nt)*64 + lane];
        const bh8 b3 = We2f[(3*8+nt)*64 + lane];
        acc[i] = __builtin_amdgcn_mfma_f32_16x16x32_bf16(af[0], b0, acc[i], 0,0,0);
        acc[i] = __builtin_amdgcn_mfma_f32_16x16x32_bf16(af[1], b1, acc[i], 0,0,0);
        acc[i] = __builtin_amdgcn_mfma_f32_16x16x32_bf16(af[2], b2, acc[i], 0,0,0);
        acc[i] = __builtin_amdgcn_mfma_f32_16x16x32_bf16(af[3], b3, acc[i], 0,0,0);
      }
      #pragma unroll
      for (int i = 0; i < 4; ++i) {
        const int nt = h4 + i;
        #pragma unroll
        for (int g = 0; g < 4; ++g) {
          const float s2 = acc[i][g];
          const unsigned int tb = bfb(s2 * sigf(s2));
          const unsigned int pb = (unsigned int)__shfl_xor((int)tb, 1, 64);
          if ((rr & 1) == 0) {
            const int unit = ((nt>>1)*4 + w)*64 + (2*(nt&1) + (rr>>3))*16 + 4*qq + g;
            tauf[unit*4 + ((rr&7)>>1)] = tb | (pb << 16);
          }
        }
      }
    }
  }
  wave_sync();

  // enc L3 (MFMA) + masked mean-pool -> rsh
  {
    bh8 tf4[4];
    #pragma unroll
    for (int kc = 0; kc < 4; ++kc)
      tf4[kc] = ((const bh8*)tauf)[(kc*4 + w)*64 + lane];
    #pragma unroll 1
    for (int half = 0; half < 2; ++half) {
      const int h4 = half*4;
      fx4 acc[4];
      #pragma unroll
      for (int i = 0; i < 4; ++i) {
        const float bv = f2sh[(h4+i)*16 + rr];
        acc[i] = (fx4){bv, bv, bv, bv};
      }
      #pragma unroll
      for (int i = 0; i < 4; ++i) {
        const int nt = h4 + i;
        const bh8 b0 = We3f[(0*8+nt)*64 + lane];
        const bh8 b1 = We3f[(1*8+nt)*64 + lane];
        const bh8 b2 = We3f[(2*8+nt)*64 + lane];
        const bh8 b3 = We3f[(3*8+nt)*64 + lane];
        acc[i] = __builtin_amdgcn_mfma_f32_16x16x32_bf16(tf4[0], b0, acc[i], 0,0,0);
        acc[i] = __builtin_amdgcn_mfma_f32_16x16x32_bf16(tf4[1], b1, acc[i], 0,0,0);
        acc[i] = __builtin_amdgcn_mfma_f32_16x16x32_bf16(tf4[2], b2, acc[i], 0,0,0);
        acc[i] = __builtin_amdgcn_mfma_f32_16x16x32_bf16(tf4[3], b3, acc[i], 0,0,0);
      }
      #pragma unroll
      for (int i = 0; i < 4; ++i) {
        float pv = mkq[0]*acc[i][0] + mkq[1]*acc[i][1]
                 + mkq[2]*acc[i][2] + mkq[3]*acc[i][3];
        pv += __shfl_xor(pv, 16, 64);
        pv += __shfl_xor(pv, 32, 64);
        if (lane < 16) dsumP[w*128 + (h4+i)*16 + lane] = pv;
      }
    }
  }
  __syncthreads();
  if (tid < 128)
    rsh[tid] = (dsumP[tid] + dsumP[128+tid] + dsumP[256+tid] + dsumP[384+tid]) * inv_msum;
  __syncthreads();

  // ================= Langevin step loop =================
  for (int st = 0; st < steps; ++st) {
    const float t = (float)st * dt;

    // zW1[k] = bd1[k] + sum_j z[j] Wd1[j,k]
    if (tid < 128) {
      float p0 = bd1[tid], p1 = 0.f, p2 = 0.f, p3 = 0.f;
      #pragma unroll 4
      for (int j = 0; j < 64; j += 4) {
        p0 = fmaf(zsh[j+0], Wd1[(j+0)*HD + tid], p0);
        p1 = fmaf(zsh[j+1], Wd1[(j+1)*HD + tid], p1);
        p2 = fmaf(zsh[j+2], Wd1[(j+2)*HD + tid], p2);
        p3 = fmaf(zsh[j+3], Wd1[(j+3)*HD + tid], p3);
      }
      zw1[tid] = (p0+p1) + (p2+p3);
    }
    __syncthreads();

    // dec L1: h1 = silu(zW1 + x*Wd1x) -> h1f (A-frag layout, kc=w slice)
    #pragma unroll
    for (int quad = 0; quad < 4; ++quad) {
      unsigned int pw[4];
      #pragma unroll
      for (int jj = 0; jj < 8; jj += 2) {
        const int k = 32*w + 8*quad + jj;
        const float sA = zw1[k]   + x0v*wx0sh[k]   + x1v*wx1sh[k];
        const float sB = zw1[k+1] + x0v*wx0sh[k+1] + x1v*wx1sh[k+1];
        pw[jj>>1] = packbf(sA*sigf(sA), sB*sigf(sB));
      }
      uint4 v4; v4.x = pw[0]; v4.y = pw[1]; v4.z = pw[2]; v4.w = pw[3];
      ((uint4*)h1f)[(w*4 + (lane>>4))*64 + quad*16 + (lane&15)] = v4;
    }
    __syncthreads();

    // fwd (MFMA): S2 = H1 @ Wd2 + bd2; emit tau (aliased scatter) and ebw
    float ebw[4];
    {
      bh8 af[4];
      #pragma unroll
      for (int kc = 0; kc < 4; ++kc)
        af[kc] = ((const bh8*)h1f)[(kc*4 + w)*64 + lane];
      wave_sync();   // af in regs before the aliased scatter below
      float da[4] = {0.f, 0.f, 0.f, 0.f};
      #pragma unroll 1
      for (int half = 0; half < 2; ++half) {
        const int h4 = half*4;
        fx4 acc[4];
        #pragma unroll
        for (int i = 0; i < 4; ++i) {
          const float bv = bd2sh[(h4+i)*16 + rr];
          acc[i] = (fx4){bv, bv, bv, bv};
        }
        #pragma unroll
        for (int i = 0; i < 4; ++i) {
          const int nt = h4 + i;
          const bh8 b0 = Wd2f[(0*8+nt)*64 + lane];
          const bh8 b1 = Wd2f[(1*8+nt)*64 + lane];
          const bh8 b2 = Wd2f[(2*8+nt)*64 + lane];
          const bh8 b3 = Wd2f[(3*8+nt)*64 + lane];
          acc[i] = __builtin_amdgcn_mfma_f32_16x16x32_bf16(af[0], b0, acc[i], 0,0,0);
          acc[i] = __builtin_amdgcn_mfma_f32_16x16x32_bf16(af[1], b1, acc[i], 0,0,0);
          acc[i] = __builtin_amdgcn_mfma_f32_16x16x32_bf16(af[2], b2, acc[i], 0,0,0);
          acc[i] = __builtin_amdgcn_mfma_f32_16x16x32_bf16(af[3], b3, acc[i], 0,0,0);
        }
        #pragma unroll
        for (int i = 0; i < 4; ++i) {
          const int nt = h4 + i;
          const float w3 = wd3sh[nt*16 + rr];
          #pragma unroll
          for (int g = 0; g < 4; ++g) {
            const float s2 = acc[i][g];
            const float sg = sigf(s2);
            da[g] = fmaf(s2*sg, w3, da[g]);
            const unsigned int tb = bfb(w3 * (sg * fmaf(s2, 1.0f - sg, 1.0f)));
            const unsigned int pb = (unsigned int)__shfl_xor((int)tb, 1, 64);
            if ((rr & 1) == 0) {
              const int unit = ((nt>>1)*4 + w)*64 + (2*(nt&1) + (rr>>3))*16 + 4*qq + g;
              tauf[unit*4 + ((rr&7)>>1)] = tb | (pb << 16);
            }
          }
        }
      }
      #pragma unroll
      for (int g = 0; g < 4; ++g) {
        float v = da[g];
        v += __shfl_xor(v, 1, 64);
        v += __shfl_xor(v, 2, 64);
        v += __shfl_xor(v, 4, 64);
        v += __shfl_xor(v, 8, 64);
        ebw[g] = t * mkq[g] * (v + bd3v - yq[g]);
      }
    }
    wave_sync();

    // bwd (MFMA): U = TAU @ Wd2^T; dsum[k] = colsum(ebw * silu'(s1) * U)
    {
      bh8 tf4[4];
      #pragma unroll
      for (int kc = 0; kc < 4; ++kc)
        tf4[kc] = ((const bh8*)tauf)[(kc*4 + w)*64 + lane];
      #pragma unroll 1
      for (int half = 0; half < 2; ++half) {
        const int h4 = half*4;
        fx4 u[4];
        #pragma unroll
        for (int i = 0; i < 4; ++i) u[i] = (fx4){0.f, 0.f, 0.f, 0.f};
        #pragma unroll
        for (int i = 0; i < 4; ++i) {
          const int nt = h4 + i;
          const bh8 b0 = Wd2Tf[(0*8+nt)*64 + lane];
          const bh8 b1 = Wd2Tf[(1*8+nt)*64 + lane];
          const bh8 b2 = Wd2Tf[(2*8+nt)*64 + lane];
          const bh8 b3 = Wd2Tf[(3*8+nt)*64 + lane];
          u[i] = __builtin_amdgcn_mfma_f32_16x16x32_bf16(tf4[0], b0, u[i], 0,0,0);
          u[i] = __builtin_amdgcn_mfma_f32_16x16x32_bf16(tf4[1], b1, u[i], 0,0,0);
          u[i] = __builtin_amdgcn_mfma_f32_16x16x32_bf16(tf4[2], b2, u[i], 0,0,0);
          u[i] = __builtin_amdgcn_mfma_f32_16x16x32_bf16(tf4[3], b3, u[i], 0,0,0);
        }
        #pragma unroll
        for (int i = 0; i < 4; ++i) {
          const int nt = h4 + i;
          const float zv = zw1[nt*16 + rr];
          const float wa = wx0sh[nt*16 + rr];
          const float wb = wx1sh[nt*16 + rr];
          float snt = 0.f;
          #pragma unroll
          for (int g = 0; g < 4; ++g) {
            const float s1 = zv + x0q[g]*wa + x1q[g]*wb;
            const float sg = sigf(s1);
            snt += ebw[g] * (sg * fmaf(s1, 1.0f - sg, 1.0f)) * u[i][g];
          }
          snt += __shfl_xor(snt, 16, 64);
          snt += __shfl_xor(snt, 32, 64);
          if (lane < 16) dsumP[w*128 + nt*16 + lane] = snt;
        }
      }
    }
    __syncthreads();

    // dsum combine + drift f1
    if (tid < 128) {
      dsumC[tid] = dsumP[tid] + dsumP[128+tid] + dsumP[256+tid] + dsumP[384+tid];
      float p0 = fmaf(t, Wf1[192*HD + tid], bf1[tid]);
      float p1 = 0.f, p2 = 0.f, p3 = 0.f;
      #pragma unroll 4
      for (int j = 0; j < 64; j += 4) {
        p0 = fmaf(zsh[j+0], Wf1[(j+0)*HD + tid], p0);
        p1 = fmaf(zsh[j+1], Wf1[(j+1)*HD + tid], p1);
        p2 = fmaf(zsh[j+2], Wf1[(j+2)*HD + tid], p2);
        p3 = fmaf(zsh[j+3], Wf1[(j+3)*HD + tid], p3);
      }
      #pragma unroll 4
      for (int j = 0; j < 128; j += 4) {
        p0 = fmaf(rsh[j+0], Wf1[(64+j+0)*HD + tid], p0);
        p1 = fmaf(rsh[j+1], Wf1[(64+j+1)*HD + tid], p1);
        p2 = fmaf(rsh[j+2], Wf1[(64+j+2)*HD + tid], p2);
        p3 = fmaf(rsh[j+3], Wf1[(64+j+3)*HD + tid], p3);
      }
      const float a = (p0+p1) + (p2+p3);
      f1sh[tid] = a * sigf(a);
    }
    __syncthreads();
    if (tid < 128) {
      float p0 = bf2[tid], p1 = 0.f, p2 = 0.f, p3 = 0.f;
      #pragma unroll 4
      for (int j = 0; j < 128; j += 4) {
        p0 = fmaf(f1sh[j+0], Wf2[(j+0)*HD + tid], p0);
        p1 = fmaf(f1sh[j+1], Wf2[(j+1)*HD + tid], p1);
        p2 = fmaf(f1sh[j+2], Wf2[(j+2)*HD + tid], p2);
        p3 = fmaf(f1sh[j+3], Wf2[(j+3)*HD + tid], p3);
      }
      const float a = (p0+p1) + (p2+p3);
      f2sh[tid] = a * sigf(a);
    }
    __syncthreads();
    if (tid < 128) {
      if (tid < 64) {
        float p0 = bf3[tid], p1 = 0.f, p2 = 0.f, p3 = 0.f;
        #pragma unroll 4
        for (int h = 0; h < 128; h += 4) {
          p0 = fmaf(f2sh[h+0], Wf3[(h+0)*ZD + tid], p0);
          p1 = fmaf(f2sh[h+1], Wf3[(h+1)*ZD + tid], p1);
          p2 = fmaf(f2sh[h+2], Wf3[(h+2)*ZD + tid], p2);
          p3 = fmaf(f2sh[h+3], Wf3[(h+3)*ZD + tid], p3);
        }
        bgz[tid] = (p0+p1) + (p2+p3);              // drift output b_j
      } else {
        const int j = tid - 64;
        float p0 = 0.f, p1 = 0.f, p2 = 0.f, p3 = 0.f;
        #pragma unroll 4
        for (int h = 0; h < 128; h += 4) {
          p0 = fmaf(dsumC[h+0], Wd1[j*HD + h+0], p0);
          p1 = fmaf(dsumC[h+1], Wd1[j*HD + h+1], p1);
          p2 = fmaf(dsumC[h+2], Wd1[j*HD + h+2], p2);
          p3 = fmaf(dsumC[h+3], Wd1[j*HD + h+3], p3);
        }
        bgz[64 + j] = (p0+p1) + (p2+p3);           // gz_j (t folded into ebw)
      }
    }
    __syncthreads();
    if (tid < 64) {
      const float zold = zsh[tid];
      float g = zold + bgz[64 + tid];
      g = fminf(fmaxf(g, -100.0f), 100.0f);
      zsh[tid] = zold + (bgz[tid] - g) * dt
               + dco * noises[(size_t)st * (B_TOT * ZD) + b * ZD + tid];
    }
    __syncthreads();
  }

  if (tid < 64) out[b * ZD + tid] = zsh[tid];
}

extern "C" void kernel_launch(void* const* d_in, const int* in_sizes, int n_in,
                              void* d_out, int out_size, void* d_ws, size_t ws_size,
                              hipStream_t stream) {
  const float* x_ctx  = (const float*)d_in[0];
  const float* y_ctx  = (const float*)d_in[1];
  const float* mask   = (const float*)d_in[2];
  const float* z0     = (const float*)d_in[3];
  const float* noises = (const float*)d_in[4];
  const float* We1 = (const float*)d_in[5];  const float* be1 = (const float*)d_in[6];
  const float* We2 = (const float*)d_in[7];  const float* be2 = (const float*)d_in[8];
  const float* We3 = (const float*)d_in[9];  const float* be3 = (const float*)d_in[10];
  const float* Wd1 = (const float*)d_in[11]; const float* bd1 = (const float*)d_in[12];
  const float* Wd2 = (const float*)d_in[13]; const float* bd2 = (const float*)d_in[14];
  const float* Wd3 = (const float*)d_in[15]; const float* bd3 = (const float*)d_in[16];
  const float* Wf1 = (const float*)d_in[17]; const float* bf1 = (const float*)d_in[18];
  const float* Wf2 = (const float*)d_in[19]; const float* bf2 = (const float*)d_in[20];
  const float* Wf3 = (const float*)d_in[21]; const float* bf3 = (const float*)d_in[22];

  const int steps = in_sizes[4] / (B_TOT * ZD);
  const float dt  = 1.0f / (float)steps;
  const float dco = (float)sqrt(2.0 / (double)steps);

  ushort* wsu = (ushort*)d_ws;   // 4 bf16 frag arrays, 128 KB total

  hipLaunchKernelGGL(prep_kernel, dim3(256), dim3(256), 0, stream, Wd2, We2, We3, wsu);
  hipLaunchKernelGGL(metanets_kernel, dim3(B_TOT), dim3(256), 0, stream,
      x_ctx, y_ctx, mask, z0, noises,
      We1, be1, be2, be3,
      Wd1, bd1, bd2, Wd3, bd3,
      Wf1, bf1, Wf2, bf2, Wf3, bf3,
      wsu, (float*)d_out, steps, dt, dco);
}